// Round 11
// baseline (385.607 us; speedup 1.0000x reference)
//
#include <hip/hip_runtime.h>
#include <hip/hip_bf16.h>
#include <math.h>

namespace {

typedef unsigned long long u64;
typedef __attribute__((ext_vector_type(8))) short bf16x8;
typedef __attribute__((ext_vector_type(4))) float f32x4;
typedef __attribute__((ext_vector_type(4))) unsigned uint4e;

constexpr int KK = 5;
constexpr int K3 = 125;
constexpr int N0 = 16384, E0 = 262144;
constexpr int N1 = 4096,  E1 = 65536;
constexpr int N2 = 1024,  E2 = 16384;
constexpr int N3 = 256,   E3 = 4096;
constexpr int E_TOT = E0 + E1 + E2 + E3;     // 348160
constexpr unsigned ENC_NEG_INF = 0x007FFFFFu;
constexpr int KO2 = K3 * 64, KO3 = K3 * 64, KO4 = K3 * 128;

// ---------------- workspace layout (float-slot offsets) ----------------
constexpr size_t A_PENC1 = 0;
constexpr size_t A_PENC2 = A_PENC1 + (size_t)N1 * 32;
constexpr size_t A_PENC3 = A_PENC2 + (size_t)N2 * 64;
constexpr size_t A_PENC4 = A_PENC3 + (size_t)N3 * 64;
constexpr size_t A_PENC_END = A_PENC4 + (size_t)128 * 128;
constexpr size_t PENC_TOTAL = A_PENC_END;                  // 229376

constexpr size_t A_WT2 = A_PENC_END;
constexpr size_t A_WT3 = A_WT2 + (size_t)K3 * 64 * 32 / 2;
constexpr size_t A_WT4 = A_WT3 + (size_t)K3 * 64 * 64 / 2;

constexpr size_t A_OFF0 = A_WT4 + (size_t)K3 * 128 * 64 / 2;
constexpr size_t A_OFF1 = A_OFF0 + (N0 + 4);
constexpr size_t A_OFF2 = A_OFF1 + (N1 + 4);
constexpr size_t A_OFF3 = A_OFF2 + (N2 + 4);
constexpr size_t A_CUR0 = A_OFF3 + (N3 + 4);
constexpr size_t A_CUR1 = A_CUR0 + N0;
constexpr size_t A_CUR2 = A_CUR1 + N1;
constexpr size_t A_CUR3 = A_CUR2 + N2;
constexpr size_t A_CUR_END = A_CUR3 + N3;
constexpr size_t CUR_TOTAL = A_CUR_END - A_CUR0;           // 21760

constexpr size_t A_REC0 = (A_CUR_END + 3) & ~(size_t)3;    // 12 floats (48B) per edge
constexpr size_t A_REC1 = A_REC0 + (size_t)E0 * 12;
constexpr size_t A_REC2 = A_REC1 + (size_t)E1 * 12;
constexpr size_t A_REC3 = A_REC2 + (size_t)E2 * 12;
constexpr size_t A_Y    = (A_REC3 + (size_t)E3 * 12 + 3) & ~(size_t)3;

// grid partition constants
constexpr int NB_HIST  = (E_TOT + 255) / 256;  // 1360
constexpr int NB_SCAT0 = E0 / 256;             // 1024
constexpr int NB_SCAT1 = E1 / 256;             // 256
constexpr int NB_SCAT2 = E2 / 256;             // 64
constexpr int NB_SCAT3 = E3 / 256;             // 16
constexpr int NB_L1    = N0 / 8;               // 2048
constexpr int NB_G2    = (KO2 / 64) * ((N1 / 16) / 16);    // 125*16 = 2000
constexpr int NB_G3    = (KO3 / 64) * ((N2 / 16) / 16);    // 125*4  = 500
constexpr int NB_G4    = (KO4 / 64) * ((N3 / 16) / 16);    // 250*1  = 250
constexpr int NB_GA2   = N1 / 4;               // 1024
constexpr int NB_GA3   = N2 / 4;               // 256
constexpr int NB_GA4   = N3 / 4;               // 64

struct __align__(16) ERec {      // one CSR-ordered edge record (48 B)
    float4 q0;
    float4 q1;
    u64 kid;
    unsigned src;
    unsigned pad;
};

struct P {
    const float *x0, *W1, *root1, *b1, *root2, *b2, *root3, *b3, *root4, *b4;
    const float *ps0, *ps1, *ps2, *ps3;
    const float *W2, *W3, *W4, *fc1w, *fc1b, *fc2w, *fc2b;
    const int *src0, *dst0, *src1, *dst1, *src2, *dst2, *src3, *dst3;
    const int *cl0, *cl1, *cl2, *cl3;
    float* ws;
    float* out;
};

// ---------------- helpers ----------------
__device__ __forceinline__ float eluf(float x) { return x > 0.f ? x : expm1f(x); }

__device__ __forceinline__ unsigned enc_f(float x) {
    unsigned u = __float_as_uint(x);
    return (u & 0x80000000u) ? ~u : (u | 0x80000000u);
}
__device__ __forceinline__ float dec_fin(unsigned u) {
    u = (u & 0x80000000u) ? (u & 0x7fffffffu) : ~u;
    float v = __uint_as_float(u);
    return isfinite(v) ? v : 0.f;
}
__device__ __forceinline__ float bf2f(unsigned short u) {
    return __uint_as_float((unsigned)u << 16);
}
__device__ __forceinline__ unsigned short f2bf(float v) {
    __hip_bfloat16 h = __float2bfloat16(v);
    return *reinterpret_cast<unsigned short*>(&h);
}

// nontemporal ERec load/store (3 x 16B)
__device__ __forceinline__ ERec nt_load_rec(const ERec* p) {
    const uint4e* q = (const uint4e*)p;
    uint4e a = __builtin_nontemporal_load(q);
    uint4e b = __builtin_nontemporal_load(q + 1);
    uint4e c = __builtin_nontemporal_load(q + 2);
    ERec r;
    r.q0 = make_float4(__uint_as_float(a[0]), __uint_as_float(a[1]),
                       __uint_as_float(a[2]), __uint_as_float(a[3]));
    r.q1 = make_float4(__uint_as_float(b[0]), __uint_as_float(b[1]),
                       __uint_as_float(b[2]), __uint_as_float(b[3]));
    r.kid = (u64)c[0] | ((u64)c[1] << 32);
    r.src = c[2];
    r.pad = c[3];
    return r;
}
__device__ __forceinline__ void nt_store_rec(ERec* p, const ERec& r) {
    uint4e a = {__float_as_uint(r.q0.x), __float_as_uint(r.q0.y),
                __float_as_uint(r.q0.z), __float_as_uint(r.q0.w)};
    uint4e b = {__float_as_uint(r.q1.x), __float_as_uint(r.q1.y),
                __float_as_uint(r.q1.z), __float_as_uint(r.q1.w)};
    uint4e c = {(unsigned)(r.kid & 0xffffffffu), (unsigned)(r.kid >> 32), r.src, r.pad};
    uint4e* q = (uint4e*)p;
    __builtin_nontemporal_store(a, q);
    __builtin_nontemporal_store(b, q + 1);
    __builtin_nontemporal_store(c, q + 2);
}
__device__ __forceinline__ unsigned short nt_lds(const unsigned short* p) {
    return __builtin_nontemporal_load(p);
}

__device__ __forceinline__ void decode_edge(const float* __restrict__ pseudo, int e,
                                            float bas[8], int kid[8]) {
    float v0 = pseudo[e * 3 + 0] * (KK - 1);
    float v1 = pseudo[e * 3 + 1] * (KK - 1);
    float v2 = pseudo[e * 3 + 2] * (KK - 1);
    float f0 = fminf(fmaxf(floorf(v0), 0.f), (float)(KK - 2));
    float f1 = fminf(fmaxf(floorf(v1), 0.f), (float)(KK - 2));
    float f2 = fminf(fmaxf(floorf(v2), 0.f), (float)(KK - 2));
    int lo0 = (int)f0, lo1 = (int)f1, lo2 = (int)f2;
    float fr0 = v0 - f0, fr1 = v1 - f1, fr2 = v2 - f2;
#pragma unroll
    for (int c = 0; c < 8; ++c) {
        int b0 = c & 1, b1 = (c >> 1) & 1, b2 = (c >> 2) & 1;
        kid[c] = (lo0 + b0) + (lo1 + b1) * KK + (lo2 + b2) * KK * KK;
        bas[c] = (b0 ? fr0 : 1.f - fr0) * (b1 ? fr1 : 1.f - fr1) * (b2 ? fr2 : 1.f - fr2);
    }
}

// ---------------- unit: W[k][i][o] f32 -> wt[(k*OUT+o)][i] bf16 (32-row halves) ----
__device__ void wt_unit(const float* __restrict__ W, unsigned short* __restrict__ wt,
                        int IN, int OUT, int k, float* smem) {
    const float* Wk = W + (size_t)k * IN * OUT;
    unsigned short* wk = wt + (size_t)k * IN * OUT;
    int halves = IN / 32;
    for (int h = 0; h < halves; ++h) {
        __syncthreads();
        for (int idx = threadIdx.x; idx < 32 * OUT; idx += 256) {
            int i = idx / OUT, o = idx % OUT;
            smem[i * (OUT + 1) + o] = Wk[(size_t)(h * 32 + i) * OUT + o];
        }
        __syncthreads();
        for (int idx = threadIdx.x; idx < OUT * 32; idx += 256) {
            int o = idx / 32, i = idx % 32;
            wk[(size_t)o * IN + h * 32 + i] = f2bf(smem[i * (OUT + 1) + o]);
        }
    }
}

// ---------------- unit: decode + scatter one 256-edge slab into CSR records -------
__device__ void scat_unit(int u, const float* __restrict__ ps,
                          const int* __restrict__ dst, const int* __restrict__ srcA,
                          int* __restrict__ cur, ERec* __restrict__ rec, int E) {
    int e = u * 256 + threadIdx.x;
    if (e >= E) return;
    float b[8]; int k[8];
    decode_edge(ps, e, b, k);
    u64 pk = 0;
#pragma unroll
    for (int c = 0; c < 8; ++c) pk |= (u64)(unsigned)k[c] << (8 * c);
    int q = atomicAdd(&cur[dst[e]], 1);
    ERec r;
    r.q0 = make_float4(b[0], b[1], b[2], b[3]);
    r.q1 = make_float4(b[4], b[5], b[6], b[7]);
    r.kid = pk;
    r.src = (unsigned)srcA[e];
    r.pad = 0;
    nt_store_rec(&rec[q], r);
}

// ---------------- unit: one 16n x 64ko MFMA tile (nt y store) ----------------
template <int IN>
__device__ __forceinline__ void gemm_tile(int n0, int ko0,
                                          const unsigned* __restrict__ penc,
                                          const unsigned short* __restrict__ wt,
                                          unsigned short* __restrict__ y, int KO) {
    int lane = threadIdx.x & 63;
    int l15 = lane & 15;
    int kk = (lane >> 4) << 3;
    int rbase = (lane >> 4) << 2;
    f32x4 acc[4];
#pragma unroll
    for (int t = 0; t < 4; ++t) acc[t] = (f32x4){0.f, 0.f, 0.f, 0.f};
#pragma unroll
    for (int s = 0; s < IN / 32; ++s) {
        const unsigned* pp = penc + (size_t)(n0 + l15) * IN + s * 32 + kk;
        uint4 u0 = *(const uint4*)pp;
        uint4 u1 = *(const uint4*)(pp + 4);
        unsigned uu[8] = {u0.x, u0.y, u0.z, u0.w, u1.x, u1.y, u1.z, u1.w};
        bf16x8 bfrag;
#pragma unroll
        for (int t = 0; t < 8; ++t) bfrag[t] = (short)f2bf(dec_fin(uu[t]));
#pragma unroll
        for (int t = 0; t < 4; ++t) {
            bf16x8 afrag = *(const bf16x8*)(wt + (size_t)(ko0 + t * 16 + l15) * IN + s * 32 + kk);
            acc[t] = __builtin_amdgcn_mfma_f32_16x16x32_bf16(afrag, bfrag, acc[t], 0, 0, 0);
        }
    }
#pragma unroll
    for (int t = 0; t < 4; ++t) {
        u64 pk = (u64)f2bf(acc[t][0]) | ((u64)f2bf(acc[t][1]) << 16)
               | ((u64)f2bf(acc[t][2]) << 32) | ((u64)f2bf(acc[t][3]) << 48);
        __builtin_nontemporal_store(pk, (u64*)(y + (size_t)(n0 + l15) * KO + ko0 + t * 16 + rbase));
    }
}

// block = one ko-group x 16 n-tiles (wt slice stays L1-hot)
template <int IN>
__device__ void gemm_blk(int bid, const unsigned* __restrict__ penc,
                         const unsigned short* __restrict__ wt,
                         unsigned short* __restrict__ y, int N, int KO) {
    int nGrp = (N >> 4) >> 4;              // n-chunks of 16 tiles (>=1)
    int kog = bid / nGrp;
    int nchunk = bid % nGrp;
    int wsub = threadIdx.x >> 6;
    int ko0 = kog << 6;
#pragma unroll
    for (int it = 0; it < 4; ++it) {
        int ntile = (nchunk << 4) + (it << 2) + wsub;
        gemm_tile<IN>(ntile << 4, ko0, penc, wt, y, KO);
    }
}

// ---------------- unit: 4 nodes of gather+agg+finish+pool (CSR stream, nt) -------
template <int IN, int OUT>
__device__ void gather_unit(int u, const unsigned short* __restrict__ y,
                            const ERec* __restrict__ rec, const int* __restrict__ off,
                            const unsigned* __restrict__ penc_prev,
                            const float* __restrict__ root,
                            const float* __restrict__ bias,
                            const int* __restrict__ cl,
                            unsigned* __restrict__ penc) {
    constexpr int KO = K3 * OUT;
    constexpr int WPT = OUT / 64;
    int lane = threadIdx.x & 63;
    int wv = threadIdx.x >> 6;
    int n = u * 4 + wv;
    int s0 = off[n], s1 = off[n + 1];
    float acc0 = 0.f, acc1 = 0.f;
    int j = s0;
    for (; j + 2 <= s1; j += 2) {
        ERec ra = nt_load_rec(&rec[j]), rb = nt_load_rec(&rec[j + 1]);
        const unsigned short* ypa = y + (size_t)ra.src * KO + lane;
        const unsigned short* ypb = y + (size_t)rb.src * KO + lane;
        float ba[8] = {ra.q0.x, ra.q0.y, ra.q0.z, ra.q0.w, ra.q1.x, ra.q1.y, ra.q1.z, ra.q1.w};
        float bb[8] = {rb.q0.x, rb.q0.y, rb.q0.z, rb.q0.w, rb.q1.x, rb.q1.y, rb.q1.z, rb.q1.w};
        u64 ka = ra.kid, kb = rb.kid;
        float va[8], vb[8], va2[8], vb2[8];
#pragma unroll
        for (int c = 0; c < 8; ++c) {
            int kca = (int)((ka >> (8 * c)) & 255u);
            int kcb = (int)((kb >> (8 * c)) & 255u);
            va[c] = bf2f(nt_lds(ypa + (size_t)kca * OUT));
            vb[c] = bf2f(nt_lds(ypb + (size_t)kcb * OUT));
            if (WPT == 2) {
                va2[c] = bf2f(nt_lds(ypa + (size_t)kca * OUT + 64));
                vb2[c] = bf2f(nt_lds(ypb + (size_t)kcb * OUT + 64));
            }
        }
#pragma unroll
        for (int c = 0; c < 8; ++c) {
            acc0 = fmaf(ba[c], va[c], acc0);
            acc0 = fmaf(bb[c], vb[c], acc0);
            if (WPT == 2) {
                acc1 = fmaf(ba[c], va2[c], acc1);
                acc1 = fmaf(bb[c], vb2[c], acc1);
            }
        }
    }
    if (j < s1) {
        ERec r = nt_load_rec(&rec[j]);
        const unsigned short* yp = y + (size_t)r.src * KO + lane;
        float b[8] = {r.q0.x, r.q0.y, r.q0.z, r.q0.w, r.q1.x, r.q1.y, r.q1.z, r.q1.w};
        u64 k8 = r.kid;
#pragma unroll
        for (int c = 0; c < 8; ++c) {
            int kc = (int)((k8 >> (8 * c)) & 255u);
            acc0 = fmaf(b[c], bf2f(nt_lds(yp + (size_t)kc * OUT)), acc0);
            if (WPT == 2) acc1 = fmaf(b[c], bf2f(nt_lds(yp + (size_t)kc * OUT + 64)), acc1);
        }
    }
    float dg = fmaxf((float)(s1 - s0), 1.f);
    float accs[2] = {acc0, acc1};
#pragma unroll
    for (int w = 0; w < WPT; ++w) {
        int o = lane + 64 * w;
        float r = 0.f;
        for (int i = 0; i < IN; ++i)
            r = fmaf(dec_fin(penc_prev[(size_t)n * IN + i]), root[(size_t)i * OUT + o], r);
        float val = accs[w] / dg + r + bias[o];
        val = eluf(val);
        atomicMax(&penc[(size_t)cl[n] * OUT + o], enc_f(val));
    }
}

// ================= kernels =================

// K1: init penc + dst histogram (+ W2 transpose in tail blocks)
__global__ __launch_bounds__(256) void k_p1(P p) {
    __shared__ float smem[32 * 129];
    float* ws = p.ws;
    int bid = blockIdx.x;
    if (bid < NB_HIST) {
        int g = bid * 256 + threadIdx.x;
        if (g < (int)PENC_TOTAL) ((unsigned*)(ws + A_PENC1))[g] = ENC_NEG_INF;
        if (g >= E_TOT) return;
        const int* dst; int* cur; int e;
        if (g < E0)                { dst = p.dst0; cur = (int*)(ws + A_CUR0); e = g; }
        else if (g < E0 + E1)      { dst = p.dst1; cur = (int*)(ws + A_CUR1); e = g - E0; }
        else if (g < E0 + E1 + E2) { dst = p.dst2; cur = (int*)(ws + A_CUR2); e = g - E0 - E1; }
        else                       { dst = p.dst3; cur = (int*)(ws + A_CUR3); e = g - E0 - E1 - E2; }
        atomicAdd(&cur[dst[e]], 1);
    } else {
        wt_unit(p.W2, (unsigned short*)(ws + A_WT2), 32, 64, bid - NB_HIST, smem);
    }
}

// K2: exclusive scan per layer
__global__ __launch_bounds__(1024) void k_scan(P p) {
    __shared__ int ls[1024];
    float* ws = p.ws;
    int* cur; int* off; int N;
    switch (blockIdx.x) {
        case 0:  cur = (int*)(ws + A_CUR0); off = (int*)(ws + A_OFF0); N = N0; break;
        case 1:  cur = (int*)(ws + A_CUR1); off = (int*)(ws + A_OFF1); N = N1; break;
        case 2:  cur = (int*)(ws + A_CUR2); off = (int*)(ws + A_OFF2); N = N2; break;
        default: cur = (int*)(ws + A_CUR3); off = (int*)(ws + A_OFF3); N = N3; break;
    }
    int t = threadIdx.x;
    int chunk = (N + 1023) >> 10;
    int b0 = t * chunk;
    int b1 = min(b0 + chunk, N);
    int s = 0;
    for (int i = b0; i < b1; ++i) s += cur[i];
    ls[t] = s;
    __syncthreads();
    for (int d = 1; d < 1024; d <<= 1) {
        int v = (t >= d) ? ls[t - d] : 0;
        __syncthreads();
        ls[t] += v;
        __syncthreads();
    }
    int run = (t == 0) ? 0 : ls[t - 1];
    for (int i = b0; i < b1; ++i) {
        int c = cur[i];
        off[i] = run;
        cur[i] = run;
        run += c;
    }
    if (t == 1023) off[N] = run;
}

// K3: scatter-decode layer-0 edges into CSR records
__global__ __launch_bounds__(256) void k_p2(P p) {
    scat_unit(blockIdx.x, p.ps0, p.dst0, p.src0,
              (int*)(p.ws + A_CUR0), (ERec*)(p.ws + A_REC0), E0);
}

// K4: layer-1 aggregation (+ layer-1 edge scatter in tail blocks)
__global__ __launch_bounds__(256) void k_l1(P p) {
    __shared__ float wlds[K3 * 32];
    float* ws = p.ws;
    int bid = blockIdx.x;
    if (bid >= NB_L1) {
        scat_unit(bid - NB_L1, p.ps1, p.dst1, p.src1,
                  (int*)(ws + A_CUR1), (ERec*)(ws + A_REC1), E1);
        return;
    }
    for (int i = threadIdx.x; i < K3 * 32; i += 256) wlds[i] = p.W1[i];
    __syncthreads();
    const ERec* rec = (const ERec*)(ws + A_REC0);
    const int* off = (const int*)(ws + A_OFF0);
    unsigned* penc = (unsigned*)(ws + A_PENC1);
    int o = threadIdx.x & 31;
    int nsub = threadIdx.x >> 5;
    int n = bid * 8 + nsub;
    int s0 = off[n], s1 = off[n + 1];
    float acc = 0.f;
    int j = s0;
    for (; j + 2 <= s1; j += 2) {
        ERec ra = nt_load_rec(&rec[j]), rb = nt_load_rec(&rec[j + 1]);
        u64 ka = ra.kid, kb = rb.kid;
        float xa = p.x0[ra.src], xb = p.x0[rb.src];
        float ma, mb;
        ma  = ra.q0.x * wlds[((int)( ka        & 255u)) * 32 + o];
        ma += ra.q0.y * wlds[((int)((ka >>  8) & 255u)) * 32 + o];
        ma += ra.q0.z * wlds[((int)((ka >> 16) & 255u)) * 32 + o];
        ma += ra.q0.w * wlds[((int)((ka >> 24) & 255u)) * 32 + o];
        ma += ra.q1.x * wlds[((int)((ka >> 32) & 255u)) * 32 + o];
        ma += ra.q1.y * wlds[((int)((ka >> 40) & 255u)) * 32 + o];
        ma += ra.q1.z * wlds[((int)((ka >> 48) & 255u)) * 32 + o];
        ma += ra.q1.w * wlds[((int)((ka >> 56) & 255u)) * 32 + o];
        mb  = rb.q0.x * wlds[((int)( kb        & 255u)) * 32 + o];
        mb += rb.q0.y * wlds[((int)((kb >>  8) & 255u)) * 32 + o];
        mb += rb.q0.z * wlds[((int)((kb >> 16) & 255u)) * 32 + o];
        mb += rb.q0.w * wlds[((int)((kb >> 24) & 255u)) * 32 + o];
        mb += rb.q1.x * wlds[((int)((kb >> 32) & 255u)) * 32 + o];
        mb += rb.q1.y * wlds[((int)((kb >> 40) & 255u)) * 32 + o];
        mb += rb.q1.z * wlds[((int)((kb >> 48) & 255u)) * 32 + o];
        mb += rb.q1.w * wlds[((int)((kb >> 56) & 255u)) * 32 + o];
        acc = fmaf(xa, ma, fmaf(xb, mb, acc));
    }
    if (j < s1) {
        ERec r = nt_load_rec(&rec[j]);
        u64 k8 = r.kid;
        float xv = p.x0[r.src];
        float m;
        m  = r.q0.x * wlds[((int)( k8        & 255u)) * 32 + o];
        m += r.q0.y * wlds[((int)((k8 >>  8) & 255u)) * 32 + o];
        m += r.q0.z * wlds[((int)((k8 >> 16) & 255u)) * 32 + o];
        m += r.q0.w * wlds[((int)((k8 >> 24) & 255u)) * 32 + o];
        m += r.q1.x * wlds[((int)((k8 >> 32) & 255u)) * 32 + o];
        m += r.q1.y * wlds[((int)((k8 >> 40) & 255u)) * 32 + o];
        m += r.q1.z * wlds[((int)((k8 >> 48) & 255u)) * 32 + o];
        m += r.q1.w * wlds[((int)((k8 >> 56) & 255u)) * 32 + o];
        acc = fmaf(xv, m, acc);
    }
    float dg = fmaxf((float)(s1 - s0), 1.f);
    float val = acc / dg + p.x0[n] * p.root1[o] + p.b1[o];
    val = eluf(val);
    atomicMax(&penc[(size_t)p.cl0[n] * 32 + o], enc_f(val));
}

// K5: gemm layer-2 (+ L2 scatter + W3/W4 transpose in tail blocks)
__global__ __launch_bounds__(256) void k_g2(P p) {
    __shared__ float smem[32 * 129];
    float* ws = p.ws;
    int bid = blockIdx.x;
    if (bid < NB_G2) {
        gemm_blk<32>(bid, (unsigned*)(ws + A_PENC1), (unsigned short*)(ws + A_WT2),
                     (unsigned short*)(ws + A_Y), N1, KO2);
    } else if (bid < NB_G2 + NB_SCAT2) {
        scat_unit(bid - NB_G2, p.ps2, p.dst2, p.src2,
                  (int*)(ws + A_CUR2), (ERec*)(ws + A_REC2), E2);
    } else if (bid < NB_G2 + NB_SCAT2 + K3) {
        wt_unit(p.W3, (unsigned short*)(ws + A_WT3), 64, 64, bid - NB_G2 - NB_SCAT2, smem);
    } else {
        wt_unit(p.W4, (unsigned short*)(ws + A_WT4), 64, 128, bid - NB_G2 - NB_SCAT2 - K3, smem);
    }
}

// K6: gather layer-2 (+ L3 scatter in tail blocks)
__global__ __launch_bounds__(256) void k_ga2(P p) {
    float* ws = p.ws;
    int bid = blockIdx.x;
    if (bid < NB_GA2) {
        gather_unit<32, 64>(bid, (unsigned short*)(ws + A_Y), (const ERec*)(ws + A_REC1),
                            (const int*)(ws + A_OFF1), (unsigned*)(ws + A_PENC1),
                            p.root2, p.b2, p.cl1, (unsigned*)(ws + A_PENC2));
    } else {
        scat_unit(bid - NB_GA2, p.ps3, p.dst3, p.src3,
                  (int*)(ws + A_CUR3), (ERec*)(ws + A_REC3), E3);
    }
}

// K7-K10: layer 3/4 gemm+gather
__global__ __launch_bounds__(256) void k_g3(P p) {
    gemm_blk<64>(blockIdx.x, (unsigned*)(p.ws + A_PENC2), (unsigned short*)(p.ws + A_WT3),
                 (unsigned short*)(p.ws + A_Y), N2, KO3);
}
__global__ __launch_bounds__(256) void k_ga3(P p) {
    gather_unit<64, 64>(blockIdx.x, (unsigned short*)(p.ws + A_Y), (const ERec*)(p.ws + A_REC2),
                        (const int*)(p.ws + A_OFF2), (unsigned*)(p.ws + A_PENC2),
                        p.root3, p.b3, p.cl2, (unsigned*)(p.ws + A_PENC3));
}
__global__ __launch_bounds__(256) void k_g4(P p) {
    gemm_blk<64>(blockIdx.x, (unsigned*)(p.ws + A_PENC3), (unsigned short*)(p.ws + A_WT4),
                 (unsigned short*)(p.ws + A_Y), N3, KO4);
}
__global__ __launch_bounds__(256) void k_ga4(P p) {
    gather_unit<64, 128>(blockIdx.x, (unsigned short*)(p.ws + A_Y), (const ERec*)(p.ws + A_REC3),
                         (const int*)(p.ws + A_OFF3), (unsigned*)(p.ws + A_PENC3),
                         p.root4, p.b4, p.cl3, (unsigned*)(p.ws + A_PENC4));
}

// K11: fused FC head: fc1 + ELU + fc2 + log_softmax, one block per batch row
__global__ __launch_bounds__(1024) void k_fc(P p) {
    __shared__ float xs[1024];
    __shared__ float part[4][257];
    __shared__ float h[256];
    __shared__ float l[10];
    __shared__ float red[2];
    int bq = blockIdx.x;
    int t = threadIdx.x;
    const unsigned* penc4 = (const unsigned*)(p.ws + A_PENC4);
    xs[t] = dec_fin(penc4[(size_t)bq * 1024 + t]);
    __syncthreads();
    int o = t & 255, sl = t >> 8;
    const float* wp = p.fc1w + (size_t)(sl * 256) * 256 + o;
    const float* xp = xs + sl * 256;
    float acc = 0.f;
#pragma unroll 8
    for (int k = 0; k < 256; ++k)
        acc = fmaf(xp[k], wp[(size_t)k * 256], acc);
    part[sl][o] = acc;
    __syncthreads();
    if (t < 256) {
        float v = part[0][t] + part[1][t] + part[2][t] + part[3][t] + p.fc1b[t];
        h[t] = eluf(v);
    }
    __syncthreads();
    if (t < 10) {
        float a2 = p.fc2b[t];
        for (int q = 0; q < 256; ++q)
            a2 = fmaf(h[q], p.fc2w[(size_t)q * 10 + t], a2);
        l[t] = a2;
    }
    __syncthreads();
    if (t == 0) {
        float m = l[0];
        for (int i = 1; i < 10; ++i) m = fmaxf(m, l[i]);
        float s = 0.f;
        for (int i = 0; i < 10; ++i) s += expf(l[i] - m);
        red[0] = m;
        red[1] = logf(s);
    }
    __syncthreads();
    if (t < 10) p.out[(size_t)bq * 10 + t] = l[t] - red[0] - red[1];
}

} // namespace

extern "C" void kernel_launch(void* const* d_in, const int* in_sizes, int n_in,
                              void* d_out, int out_size, void* d_ws, size_t ws_size,
                              hipStream_t stream) {
    P p;
    p.x0    = (const float*)d_in[0];
    p.ps0   = (const float*)d_in[1];
    p.ps1   = (const float*)d_in[2];
    p.ps2   = (const float*)d_in[3];
    p.ps3   = (const float*)d_in[4];
    p.W1    = (const float*)d_in[5];
    p.root1 = (const float*)d_in[6];
    p.b1    = (const float*)d_in[7];
    p.W2    = (const float*)d_in[8];
    p.root2 = (const float*)d_in[9];
    p.b2    = (const float*)d_in[10];
    p.W3    = (const float*)d_in[11];
    p.root3 = (const float*)d_in[12];
    p.b3    = (const float*)d_in[13];
    p.W4    = (const float*)d_in[14];
    p.root4 = (const float*)d_in[15];
    p.b4    = (const float*)d_in[16];
    p.fc1w  = (const float*)d_in[17];
    p.fc1b  = (const float*)d_in[18];
    p.fc2w  = (const float*)d_in[19];
    p.fc2b  = (const float*)d_in[20];
    p.src0 = (const int*)d_in[21];
    p.dst0 = (const int*)d_in[22];
    p.src1 = (const int*)d_in[23];
    p.dst1 = (const int*)d_in[24];
    p.src2 = (const int*)d_in[25];
    p.dst2 = (const int*)d_in[26];
    p.src3 = (const int*)d_in[27];
    p.dst3 = (const int*)d_in[28];
    p.cl0  = (const int*)d_in[29];
    p.cl1  = (const int*)d_in[30];
    p.cl2  = (const int*)d_in[31];
    p.cl3  = (const int*)d_in[32];
    p.ws = (float*)d_ws;
    p.out = (float*)d_out;

    hipMemsetAsync(p.ws + A_CUR0, 0, CUR_TOTAL * sizeof(int), stream);

    k_p1 <<<NB_HIST + K3, 256, 0, stream>>>(p);
    k_scan<<<4, 1024, 0, stream>>>(p);
    k_p2 <<<NB_SCAT0, 256, 0, stream>>>(p);
    k_l1 <<<NB_L1 + NB_SCAT1, 256, 0, stream>>>(p);
    k_g2 <<<NB_G2 + NB_SCAT2 + 2 * K3, 256, 0, stream>>>(p);
    k_ga2<<<NB_GA2 + NB_SCAT3, 256, 0, stream>>>(p);
    k_g3 <<<NB_G3, 256, 0, stream>>>(p);
    k_ga3<<<NB_GA3, 256, 0, stream>>>(p);
    k_g4 <<<NB_G4, 256, 0, stream>>>(p);
    k_ga4<<<NB_GA4, 256, 0, stream>>>(p);
    k_fc <<<16, 1024, 0, stream>>>(p);
}

// Round 13
// 322.754 us; speedup vs baseline: 1.1947x; 1.1947x over previous
//
#include <hip/hip_runtime.h>
#include <hip/hip_bf16.h>
#include <math.h>

namespace {

typedef unsigned long long u64;
typedef __attribute__((ext_vector_type(8))) short bf16x8;
typedef __attribute__((ext_vector_type(4))) float f32x4;

constexpr int KK = 5;
constexpr int K3 = 125;
constexpr int N0 = 16384, E0 = 262144;
constexpr int N1 = 4096,  E1 = 65536;
constexpr int N2 = 1024,  E2 = 16384;
constexpr int N3 = 256,   E3 = 4096;
constexpr int E_TOT = E0 + E1 + E2 + E3;     // 348160
constexpr unsigned ENC_NEG_INF = 0x007FFFFFu;
constexpr int KO2 = K3 * 64, KO3 = K3 * 64, KO4 = K3 * 128;

// ---------------- workspace layout (float-slot offsets) ----------------
constexpr size_t A_PENC1 = 0;
constexpr size_t A_PENC2 = A_PENC1 + (size_t)N1 * 32;
constexpr size_t A_PENC3 = A_PENC2 + (size_t)N2 * 64;
constexpr size_t A_PENC4 = A_PENC3 + (size_t)N3 * 64;
constexpr size_t A_PENC_END = A_PENC4 + (size_t)128 * 128;
constexpr size_t PENC_TOTAL = A_PENC_END;                  // 229376

constexpr size_t A_WT2 = A_PENC_END;
constexpr size_t A_WT3 = A_WT2 + (size_t)K3 * 64 * 32 / 2;
constexpr size_t A_WT4 = A_WT3 + (size_t)K3 * 64 * 64 / 2;

constexpr size_t A_OFF0 = A_WT4 + (size_t)K3 * 128 * 64 / 2;
constexpr size_t A_OFF1 = A_OFF0 + (N0 + 4);
constexpr size_t A_OFF2 = A_OFF1 + (N1 + 4);
constexpr size_t A_OFF3 = A_OFF2 + (N2 + 4);
constexpr size_t A_CUR0 = A_OFF3 + (N3 + 4);
constexpr size_t A_CUR1 = A_CUR0 + N0;
constexpr size_t A_CUR2 = A_CUR1 + N1;
constexpr size_t A_CUR3 = A_CUR2 + N2;
constexpr size_t A_CUR_END = A_CUR3 + N3;
constexpr size_t CUR_TOTAL = A_CUR_END - A_CUR0;           // 21760

constexpr size_t A_REC0 = (A_CUR_END + 3) & ~(size_t)3;    // 12 floats (48B) per edge
constexpr size_t A_REC1 = A_REC0 + (size_t)E0 * 12;
constexpr size_t A_REC2 = A_REC1 + (size_t)E1 * 12;
constexpr size_t A_REC3 = A_REC2 + (size_t)E2 * 12;
constexpr size_t A_Y    = (A_REC3 + (size_t)E3 * 12 + 3) & ~(size_t)3;

// grid partition constants
constexpr int NB_HIST  = (E_TOT + 255) / 256;  // 1360
constexpr int NB_SCAT0 = E0 / 256;             // 1024
constexpr int NB_SCAT1 = E1 / 256;             // 256
constexpr int NB_SCAT2 = E2 / 256;             // 64
constexpr int NB_SCAT3 = E3 / 256;             // 16
constexpr int NB_L1    = N0 / 8;               // 2048
constexpr int NB_G2    = (KO2 / 64) * ((N1 / 16) / 16);    // 125*16 = 2000
constexpr int NB_G3    = (KO3 / 64) * ((N2 / 16) / 16);    // 125*4  = 500
constexpr int NB_G4    = (KO4 / 64) * ((N3 / 16) / 16);    // 250*1  = 250
constexpr int NB_GA2   = N1 / 4;               // 1024
constexpr int NB_GA3   = N2 / 4;               // 256
constexpr int NB_GA4   = N3 / 4;               // 64

constexpr int STG_STRIDE = 72;                 // padded ushort stride (144 B, 16B-aligned)
constexpr int STG_PER_WAVE = 16 * STG_STRIDE;  // 1152 ushorts = 2304 B

struct __align__(16) ERec {      // one CSR-ordered edge record (48 B)
    float4 q0;
    float4 q1;
    u64 kid;
    unsigned src;
    unsigned pad;
};

struct P {
    const float *x0, *W1, *root1, *b1, *root2, *b2, *root3, *b3, *root4, *b4;
    const float *ps0, *ps1, *ps2, *ps3;
    const float *W2, *W3, *W4, *fc1w, *fc1b, *fc2w, *fc2b;
    const int *src0, *dst0, *src1, *dst1, *src2, *dst2, *src3, *dst3;
    const int *cl0, *cl1, *cl2, *cl3;
    float* ws;
    float* out;
};

// ---------------- helpers ----------------
__device__ __forceinline__ float eluf(float x) { return x > 0.f ? x : expm1f(x); }

__device__ __forceinline__ unsigned enc_f(float x) {
    unsigned u = __float_as_uint(x);
    return (u & 0x80000000u) ? ~u : (u | 0x80000000u);
}
__device__ __forceinline__ float dec_fin(unsigned u) {
    u = (u & 0x80000000u) ? (u & 0x7fffffffu) : ~u;
    float v = __uint_as_float(u);
    return isfinite(v) ? v : 0.f;
}
__device__ __forceinline__ float bf2f(unsigned short u) {
    return __uint_as_float((unsigned)u << 16);
}
__device__ __forceinline__ unsigned short f2bf(float v) {
    __hip_bfloat16 h = __float2bfloat16(v);
    return *reinterpret_cast<unsigned short*>(&h);
}

__device__ __forceinline__ void decode_edge(const float* __restrict__ pseudo, int e,
                                            float bas[8], int kid[8]) {
    float v0 = pseudo[e * 3 + 0] * (KK - 1);
    float v1 = pseudo[e * 3 + 1] * (KK - 1);
    float v2 = pseudo[e * 3 + 2] * (KK - 1);
    float f0 = fminf(fmaxf(floorf(v0), 0.f), (float)(KK - 2));
    float f1 = fminf(fmaxf(floorf(v1), 0.f), (float)(KK - 2));
    float f2 = fminf(fmaxf(floorf(v2), 0.f), (float)(KK - 2));
    int lo0 = (int)f0, lo1 = (int)f1, lo2 = (int)f2;
    float fr0 = v0 - f0, fr1 = v1 - f1, fr2 = v2 - f2;
#pragma unroll
    for (int c = 0; c < 8; ++c) {
        int b0 = c & 1, b1 = (c >> 1) & 1, b2 = (c >> 2) & 1;
        kid[c] = (lo0 + b0) + (lo1 + b1) * KK + (lo2 + b2) * KK * KK;
        bas[c] = (b0 ? fr0 : 1.f - fr0) * (b1 ? fr1 : 1.f - fr1) * (b2 ? fr2 : 1.f - fr2);
    }
}

// ---------------- unit: W[k][i][o] f32 -> wt[(k*OUT+o)][i] bf16 (32-row halves) ----
__device__ void wt_unit(const float* __restrict__ W, unsigned short* __restrict__ wt,
                        int IN, int OUT, int k, float* smem) {
    const float* Wk = W + (size_t)k * IN * OUT;
    unsigned short* wk = wt + (size_t)k * IN * OUT;
    int halves = IN / 32;
    for (int h = 0; h < halves; ++h) {
        __syncthreads();
        for (int idx = threadIdx.x; idx < 32 * OUT; idx += 256) {
            int i = idx / OUT, o = idx % OUT;
            smem[i * (OUT + 1) + o] = Wk[(size_t)(h * 32 + i) * OUT + o];
        }
        __syncthreads();
        for (int idx = threadIdx.x; idx < OUT * 32; idx += 256) {
            int o = idx / 32, i = idx % 32;
            wk[(size_t)o * IN + h * 32 + i] = f2bf(smem[i * (OUT + 1) + o]);
        }
    }
}

// ---------------- unit: decode + scatter one 256-edge slab into CSR records -------
__device__ void scat_unit(int u, const float* __restrict__ ps,
                          const int* __restrict__ dst, const int* __restrict__ srcA,
                          int* __restrict__ cur, ERec* __restrict__ rec, int E) {
    int e = u * 256 + threadIdx.x;
    if (e >= E) return;
    float b[8]; int k[8];
    decode_edge(ps, e, b, k);
    u64 pk = 0;
#pragma unroll
    for (int c = 0; c < 8; ++c) pk |= (u64)(unsigned)k[c] << (8 * c);
    int q = atomicAdd(&cur[dst[e]], 1);
    ERec r;
    r.q0 = make_float4(b[0], b[1], b[2], b[3]);
    r.q1 = make_float4(b[4], b[5], b[6], b[7]);
    r.kid = pk;
    r.src = (unsigned)srcA[e];
    r.pad = 0;
    rec[q] = r;
}

// ---------------- unit: one 16n x 64ko MFMA tile, LDS-staged coalesced store ------
template <int IN>
__device__ __forceinline__ void gemm_tile(int n0, int ko0,
                                          const unsigned* __restrict__ penc,
                                          const unsigned short* __restrict__ wt,
                                          unsigned short* __restrict__ y, int KO,
                                          unsigned short* __restrict__ stg) {
    int lane = threadIdx.x & 63;
    int l15 = lane & 15;
    int kk = (lane >> 4) << 3;
    int rbase = (lane >> 4) << 2;
    f32x4 acc[4];
#pragma unroll
    for (int t = 0; t < 4; ++t) acc[t] = (f32x4){0.f, 0.f, 0.f, 0.f};
#pragma unroll
    for (int s = 0; s < IN / 32; ++s) {
        const unsigned* pp = penc + (size_t)(n0 + l15) * IN + s * 32 + kk;
        uint4 u0 = *(const uint4*)pp;
        uint4 u1 = *(const uint4*)(pp + 4);
        unsigned uu[8] = {u0.x, u0.y, u0.z, u0.w, u1.x, u1.y, u1.z, u1.w};
        bf16x8 bfrag;
#pragma unroll
        for (int t = 0; t < 8; ++t) bfrag[t] = (short)f2bf(dec_fin(uu[t]));
#pragma unroll
        for (int t = 0; t < 4; ++t) {
            bf16x8 afrag = *(const bf16x8*)(wt + (size_t)(ko0 + t * 16 + l15) * IN + s * 32 + kk);
            acc[t] = __builtin_amdgcn_mfma_f32_16x16x32_bf16(afrag, bfrag, acc[t], 0, 0, 0);
        }
    }
    // stage tile into per-wave LDS: stg[n(l15)][ko] with padded stride
#pragma unroll
    for (int t = 0; t < 4; ++t) {
#pragma unroll
        for (int j = 0; j < 4; ++j)
            stg[l15 * STG_STRIDE + t * 16 + rbase + j] = f2bf(acc[t][j]);
    }
    // wave-synchronous: ds_write -> ds_read ordering handled via lgkmcnt
#pragma unroll
    for (int i = 0; i < 2; ++i) {
        int idx = i * 64 + lane;
        int row = idx >> 3;              // 0..15
        int off8 = (idx & 7) << 3;       // ushort offset, 16B granules
        const uint4* s = (const uint4*)(stg + row * STG_STRIDE + off8);
        uint4 v = *s;
        *(uint4*)(y + (size_t)(n0 + row) * KO + ko0 + off8) = v;
    }
}

// block = one ko-group x 16 n-tiles (wt slice stays L1-hot)
template <int IN>
__device__ void gemm_blk(int bid, const unsigned* __restrict__ penc,
                         const unsigned short* __restrict__ wt,
                         unsigned short* __restrict__ y, int N, int KO,
                         unsigned short* __restrict__ stg_base) {
    int nGrp = (N >> 4) >> 4;              // n-chunks of 16 tiles (>=1)
    int kog = bid / nGrp;
    int nchunk = bid % nGrp;
    int wsub = threadIdx.x >> 6;
    int ko0 = kog << 6;
    unsigned short* stg = stg_base + wsub * STG_PER_WAVE;
#pragma unroll
    for (int it = 0; it < 4; ++it) {
        int ntile = (nchunk << 4) + (it << 2) + wsub;
        gemm_tile<IN>(ntile << 4, ko0, penc, wt, y, KO, stg);
    }
}

// ---------------- unit: 4 nodes of gather+agg+finish+pool (CSR stream) -----------
template <int IN, int OUT>
__device__ void gather_unit(int u, const unsigned short* __restrict__ y,
                            const ERec* __restrict__ rec, const int* __restrict__ off,
                            const unsigned* __restrict__ penc_prev,
                            const float* __restrict__ root,
                            const float* __restrict__ bias,
                            const int* __restrict__ cl,
                            unsigned* __restrict__ penc) {
    constexpr int KO = K3 * OUT;
    constexpr int WPT = OUT / 64;
    int lane = threadIdx.x & 63;
    int wv = threadIdx.x >> 6;
    int n = u * 4 + wv;
    int s0 = off[n], s1 = off[n + 1];
    float acc0 = 0.f, acc1 = 0.f;
    int j = s0;
    for (; j + 2 <= s1; j += 2) {
        ERec ra = rec[j], rb = rec[j + 1];
        const unsigned short* ypa = y + (size_t)ra.src * KO + lane;
        const unsigned short* ypb = y + (size_t)rb.src * KO + lane;
        float ba[8] = {ra.q0.x, ra.q0.y, ra.q0.z, ra.q0.w, ra.q1.x, ra.q1.y, ra.q1.z, ra.q1.w};
        float bb[8] = {rb.q0.x, rb.q0.y, rb.q0.z, rb.q0.w, rb.q1.x, rb.q1.y, rb.q1.z, rb.q1.w};
        u64 ka = ra.kid, kb = rb.kid;
        float va[8], vb[8], va2[8], vb2[8];
#pragma unroll
        for (int c = 0; c < 8; ++c) {
            int kca = (int)((ka >> (8 * c)) & 255u);
            int kcb = (int)((kb >> (8 * c)) & 255u);
            va[c] = bf2f(ypa[(size_t)kca * OUT]);
            vb[c] = bf2f(ypb[(size_t)kcb * OUT]);
            if (WPT == 2) {
                va2[c] = bf2f(ypa[(size_t)kca * OUT + 64]);
                vb2[c] = bf2f(ypb[(size_t)kcb * OUT + 64]);
            }
        }
#pragma unroll
        for (int c = 0; c < 8; ++c) {
            acc0 = fmaf(ba[c], va[c], acc0);
            acc0 = fmaf(bb[c], vb[c], acc0);
            if (WPT == 2) {
                acc1 = fmaf(ba[c], va2[c], acc1);
                acc1 = fmaf(bb[c], vb2[c], acc1);
            }
        }
    }
    if (j < s1) {
        ERec r = rec[j];
        const unsigned short* yp = y + (size_t)r.src * KO + lane;
        float b[8] = {r.q0.x, r.q0.y, r.q0.z, r.q0.w, r.q1.x, r.q1.y, r.q1.z, r.q1.w};
        u64 k8 = r.kid;
#pragma unroll
        for (int c = 0; c < 8; ++c) {
            int kc = (int)((k8 >> (8 * c)) & 255u);
            acc0 = fmaf(b[c], bf2f(yp[(size_t)kc * OUT]), acc0);
            if (WPT == 2) acc1 = fmaf(b[c], bf2f(yp[(size_t)kc * OUT + 64]), acc1);
        }
    }
    float dg = fmaxf((float)(s1 - s0), 1.f);
    float accs[2] = {acc0, acc1};
#pragma unroll
    for (int w = 0; w < WPT; ++w) {
        int o = lane + 64 * w;
        float r = 0.f;
        for (int i = 0; i < IN; ++i)
            r = fmaf(dec_fin(penc_prev[(size_t)n * IN + i]), root[(size_t)i * OUT + o], r);
        float val = accs[w] / dg + r + bias[o];
        val = eluf(val);
        atomicMax(&penc[(size_t)cl[n] * OUT + o], enc_f(val));
    }
}

// ================= kernels =================

// K1: init penc + dst histogram (+ W2 transpose in tail blocks)
__global__ __launch_bounds__(256) void k_p1(P p) {
    __shared__ float smem[32 * 129];
    float* ws = p.ws;
    int bid = blockIdx.x;
    if (bid < NB_HIST) {
        int g = bid * 256 + threadIdx.x;
        if (g < (int)PENC_TOTAL) ((unsigned*)(ws + A_PENC1))[g] = ENC_NEG_INF;
        if (g >= E_TOT) return;
        const int* dst; int* cur; int e;
        if (g < E0)                { dst = p.dst0; cur = (int*)(ws + A_CUR0); e = g; }
        else if (g < E0 + E1)      { dst = p.dst1; cur = (int*)(ws + A_CUR1); e = g - E0; }
        else if (g < E0 + E1 + E2) { dst = p.dst2; cur = (int*)(ws + A_CUR2); e = g - E0 - E1; }
        else                       { dst = p.dst3; cur = (int*)(ws + A_CUR3); e = g - E0 - E1 - E2; }
        atomicAdd(&cur[dst[e]], 1);
    } else {
        wt_unit(p.W2, (unsigned short*)(ws + A_WT2), 32, 64, bid - NB_HIST, smem);
    }
}

// K2: exclusive scan per layer
__global__ __launch_bounds__(1024) void k_scan(P p) {
    __shared__ int ls[1024];
    float* ws = p.ws;
    int* cur; int* off; int N;
    switch (blockIdx.x) {
        case 0:  cur = (int*)(ws + A_CUR0); off = (int*)(ws + A_OFF0); N = N0; break;
        case 1:  cur = (int*)(ws + A_CUR1); off = (int*)(ws + A_OFF1); N = N1; break;
        case 2:  cur = (int*)(ws + A_CUR2); off = (int*)(ws + A_OFF2); N = N2; break;
        default: cur = (int*)(ws + A_CUR3); off = (int*)(ws + A_OFF3); N = N3; break;
    }
    int t = threadIdx.x;
    int chunk = (N + 1023) >> 10;
    int b0 = t * chunk;
    int b1 = min(b0 + chunk, N);
    int s = 0;
    for (int i = b0; i < b1; ++i) s += cur[i];
    ls[t] = s;
    __syncthreads();
    for (int d = 1; d < 1024; d <<= 1) {
        int v = (t >= d) ? ls[t - d] : 0;
        __syncthreads();
        ls[t] += v;
        __syncthreads();
    }
    int run = (t == 0) ? 0 : ls[t - 1];
    for (int i = b0; i < b1; ++i) {
        int c = cur[i];
        off[i] = run;
        cur[i] = run;
        run += c;
    }
    if (t == 1023) off[N] = run;
}

// K3: scatter-decode layer-0 edges into CSR records
__global__ __launch_bounds__(256) void k_p2(P p) {
    scat_unit(blockIdx.x, p.ps0, p.dst0, p.src0,
              (int*)(p.ws + A_CUR0), (ERec*)(p.ws + A_REC0), E0);
}

// K4: layer-1 aggregation (+ layer-1 edge scatter in tail blocks)
__global__ __launch_bounds__(256) void k_l1(P p) {
    __shared__ float wlds[K3 * 32];
    float* ws = p.ws;
    int bid = blockIdx.x;
    if (bid >= NB_L1) {
        scat_unit(bid - NB_L1, p.ps1, p.dst1, p.src1,
                  (int*)(ws + A_CUR1), (ERec*)(ws + A_REC1), E1);
        return;
    }
    for (int i = threadIdx.x; i < K3 * 32; i += 256) wlds[i] = p.W1[i];
    __syncthreads();
    const ERec* rec = (const ERec*)(ws + A_REC0);
    const int* off = (const int*)(ws + A_OFF0);
    unsigned* penc = (unsigned*)(ws + A_PENC1);
    int o = threadIdx.x & 31;
    int nsub = threadIdx.x >> 5;
    int n = bid * 8 + nsub;
    int s0 = off[n], s1 = off[n + 1];
    float acc = 0.f;
    int j = s0;
    for (; j + 2 <= s1; j += 2) {
        ERec ra = rec[j], rb = rec[j + 1];
        u64 ka = ra.kid, kb = rb.kid;
        float xa = p.x0[ra.src], xb = p.x0[rb.src];
        float ma, mb;
        ma  = ra.q0.x * wlds[((int)( ka        & 255u)) * 32 + o];
        ma += ra.q0.y * wlds[((int)((ka >>  8) & 255u)) * 32 + o];
        ma += ra.q0.z * wlds[((int)((ka >> 16) & 255u)) * 32 + o];
        ma += ra.q0.w * wlds[((int)((ka >> 24) & 255u)) * 32 + o];
        ma += ra.q1.x * wlds[((int)((ka >> 32) & 255u)) * 32 + o];
        ma += ra.q1.y * wlds[((int)((ka >> 40) & 255u)) * 32 + o];
        ma += ra.q1.z * wlds[((int)((ka >> 48) & 255u)) * 32 + o];
        ma += ra.q1.w * wlds[((int)((ka >> 56) & 255u)) * 32 + o];
        mb  = rb.q0.x * wlds[((int)( kb        & 255u)) * 32 + o];
        mb += rb.q0.y * wlds[((int)((kb >>  8) & 255u)) * 32 + o];
        mb += rb.q0.z * wlds[((int)((kb >> 16) & 255u)) * 32 + o];
        mb += rb.q0.w * wlds[((int)((kb >> 24) & 255u)) * 32 + o];
        mb += rb.q1.x * wlds[((int)((kb >> 32) & 255u)) * 32 + o];
        mb += rb.q1.y * wlds[((int)((kb >> 40) & 255u)) * 32 + o];
        mb += rb.q1.z * wlds[((int)((kb >> 48) & 255u)) * 32 + o];
        mb += rb.q1.w * wlds[((int)((kb >> 56) & 255u)) * 32 + o];
        acc = fmaf(xa, ma, fmaf(xb, mb, acc));
    }
    if (j < s1) {
        ERec r = rec[j];
        u64 k8 = r.kid;
        float xv = p.x0[r.src];
        float m;
        m  = r.q0.x * wlds[((int)( k8        & 255u)) * 32 + o];
        m += r.q0.y * wlds[((int)((k8 >>  8) & 255u)) * 32 + o];
        m += r.q0.z * wlds[((int)((k8 >> 16) & 255u)) * 32 + o];
        m += r.q0.w * wlds[((int)((k8 >> 24) & 255u)) * 32 + o];
        m += r.q1.x * wlds[((int)((k8 >> 32) & 255u)) * 32 + o];
        m += r.q1.y * wlds[((int)((k8 >> 40) & 255u)) * 32 + o];
        m += r.q1.z * wlds[((int)((k8 >> 48) & 255u)) * 32 + o];
        m += r.q1.w * wlds[((int)((k8 >> 56) & 255u)) * 32 + o];
        acc = fmaf(xv, m, acc);
    }
    float dg = fmaxf((float)(s1 - s0), 1.f);
    float val = acc / dg + p.x0[n] * p.root1[o] + p.b1[o];
    val = eluf(val);
    atomicMax(&penc[(size_t)p.cl0[n] * 32 + o], enc_f(val));
}

// K5: gemm layer-2 (+ L2 scatter + W3/W4 transpose in tail blocks)
__global__ __launch_bounds__(256) void k_g2(P p) {
    __shared__ float smem[32 * 129];   // 16.5 KB; gemm path uses first 9.2 KB as staging
    float* ws = p.ws;
    int bid = blockIdx.x;
    if (bid < NB_G2) {
        gemm_blk<32>(bid, (unsigned*)(ws + A_PENC1), (unsigned short*)(ws + A_WT2),
                     (unsigned short*)(ws + A_Y), N1, KO2, (unsigned short*)smem);
    } else if (bid < NB_G2 + NB_SCAT2) {
        scat_unit(bid - NB_G2, p.ps2, p.dst2, p.src2,
                  (int*)(ws + A_CUR2), (ERec*)(ws + A_REC2), E2);
    } else if (bid < NB_G2 + NB_SCAT2 + K3) {
        wt_unit(p.W3, (unsigned short*)(ws + A_WT3), 64, 64, bid - NB_G2 - NB_SCAT2, smem);
    } else {
        wt_unit(p.W4, (unsigned short*)(ws + A_WT4), 64, 128, bid - NB_G2 - NB_SCAT2 - K3, smem);
    }
}

// K6: gather layer-2 (+ L3 scatter in tail blocks)
__global__ __launch_bounds__(256) void k_ga2(P p) {
    float* ws = p.ws;
    int bid = blockIdx.x;
    if (bid < NB_GA2) {
        gather_unit<32, 64>(bid, (unsigned short*)(ws + A_Y), (const ERec*)(ws + A_REC1),
                            (const int*)(ws + A_OFF1), (unsigned*)(ws + A_PENC1),
                            p.root2, p.b2, p.cl1, (unsigned*)(ws + A_PENC2));
    } else {
        scat_unit(bid - NB_GA2, p.ps3, p.dst3, p.src3,
                  (int*)(ws + A_CUR3), (ERec*)(ws + A_REC3), E3);
    }
}

// K7-K10: layer 3/4 gemm+gather
__global__ __launch_bounds__(256) void k_g3(P p) {
    __shared__ unsigned short stg[4 * STG_PER_WAVE];
    gemm_blk<64>(blockIdx.x, (unsigned*)(p.ws + A_PENC2), (unsigned short*)(p.ws + A_WT3),
                 (unsigned short*)(p.ws + A_Y), N2, KO3, stg);
}
__global__ __launch_bounds__(256) void k_ga3(P p) {
    gather_unit<64, 64>(blockIdx.x, (unsigned short*)(p.ws + A_Y), (const ERec*)(p.ws + A_REC2),
                        (const int*)(p.ws + A_OFF2), (unsigned*)(p.ws + A_PENC2),
                        p.root3, p.b3, p.cl2, (unsigned*)(p.ws + A_PENC3));
}
__global__ __launch_bounds__(256) void k_g4(P p) {
    __shared__ unsigned short stg[4 * STG_PER_WAVE];
    gemm_blk<64>(blockIdx.x, (unsigned*)(p.ws + A_PENC3), (unsigned short*)(p.ws + A_WT4),
                 (unsigned short*)(p.ws + A_Y), N3, KO4, stg);
}
__global__ __launch_bounds__(256) void k_ga4(P p) {
    gather_unit<64, 128>(blockIdx.x, (unsigned short*)(p.ws + A_Y), (const ERec*)(p.ws + A_REC3),
                         (const int*)(p.ws + A_OFF3), (unsigned*)(p.ws + A_PENC3),
                         p.root4, p.b4, p.cl3, (unsigned*)(p.ws + A_PENC4));
}

// K11: fused FC head: fc1 + ELU + fc2 + log_softmax, one block per batch row
__global__ __launch_bounds__(1024) void k_fc(P p) {
    __shared__ float xs[1024];
    __shared__ float part[4][257];
    __shared__ float h[256];
    __shared__ float l[10];
    __shared__ float red[2];
    int bq = blockIdx.x;
    int t = threadIdx.x;
    const unsigned* penc4 = (const unsigned*)(p.ws + A_PENC4);
    xs[t] = dec_fin(penc4[(size_t)bq * 1024 + t]);
    __syncthreads();
    int o = t & 255, sl = t >> 8;
    const float* wp = p.fc1w + (size_t)(sl * 256) * 256 + o;
    const float* xp = xs + sl * 256;
    float acc = 0.f;
#pragma unroll 8
    for (int k = 0; k < 256; ++k)
        acc = fmaf(xp[k], wp[(size_t)k * 256], acc);
    part[sl][o] = acc;
    __syncthreads();
    if (t < 256) {
        float v = part[0][t] + part[1][t] + part[2][t] + part[3][t] + p.fc1b[t];
        h[t] = eluf(v);
    }
    __syncthreads();
    if (t < 10) {
        float a2 = p.fc2b[t];
        for (int q = 0; q < 256; ++q)
            a2 = fmaf(h[q], p.fc2w[(size_t)q * 10 + t], a2);
        l[t] = a2;
    }
    __syncthreads();
    if (t == 0) {
        float m = l[0];
        for (int i = 1; i < 10; ++i) m = fmaxf(m, l[i]);
        float s = 0.f;
        for (int i = 0; i < 10; ++i) s += expf(l[i] - m);
        red[0] = m;
        red[1] = logf(s);
    }
    __syncthreads();
    if (t < 10) p.out[(size_t)bq * 10 + t] = l[t] - red[0] - red[1];
}

} // namespace

extern "C" void kernel_launch(void* const* d_in, const int* in_sizes, int n_in,
                              void* d_out, int out_size, void* d_ws, size_t ws_size,
                              hipStream_t stream) {
    P p;
    p.x0    = (const float*)d_in[0];
    p.ps0   = (const float*)d_in[1];
    p.ps1   = (const float*)d_in[2];
    p.ps2   = (const float*)d_in[3];
    p.ps3   = (const float*)d_in[4];
    p.W1    = (const float*)d_in[5];
    p.root1 = (const float*)d_in[6];
    p.b1    = (const float*)d_in[7];
    p.W2    = (const float*)d_in[8];
    p.root2 = (const float*)d_in[9];
    p.b2    = (const float*)d_in[10];
    p.W3    = (const float*)d_in[11];
    p.root3 = (const float*)d_in[12];
    p.b3    = (const float*)d_in[13];
    p.W4    = (const float*)d_in[14];
    p.root4 = (const float*)d_in[15];
    p.b4    = (const float*)d_in[16];
    p.fc1w  = (const float*)d_in[17];
    p.fc1b  = (const float*)d_in[18];
    p.fc2w  = (const float*)d_in[19];
    p.fc2b  = (const float*)d_in[20];
    p.src0 = (const int*)d_in[21];
    p.dst0 = (const int*)d_in[22];
    p.src1 = (const int*)d_in[23];
    p.dst1 = (const int*)d_in[24];
    p.src2 = (const int*)d_in[25];
    p.dst2 = (const int*)d_in[26];
    p.src3 = (const int*)d_in[27];
    p.dst3 = (const int*)d_in[28];
    p.cl0  = (const int*)d_in[29];
    p.cl1  = (const int*)d_in[30];
    p.cl2  = (const int*)d_in[31];
    p.cl3  = (const int*)d_in[32];
    p.ws = (float*)d_ws;
    p.out = (float*)d_out;

    hipMemsetAsync(p.ws + A_CUR0, 0, CUR_TOTAL * sizeof(int), stream);

    k_p1 <<<NB_HIST + K3, 256, 0, stream>>>(p);
    k_scan<<<4, 1024, 0, stream>>>(p);
    k_p2 <<<NB_SCAT0, 256, 0, stream>>>(p);
    k_l1 <<<NB_L1 + NB_SCAT1, 256, 0, stream>>>(p);
    k_g2 <<<NB_G2 + NB_SCAT2 + 2 * K3, 256, 0, stream>>>(p);
    k_ga2<<<NB_GA2 + NB_SCAT3, 256, 0, stream>>>(p);
    k_g3 <<<NB_G3, 256, 0, stream>>>(p);
    k_ga3<<<NB_GA3, 256, 0, stream>>>(p);
    k_g4 <<<NB_G4, 256, 0, stream>>>(p);
    k_ga4<<<NB_GA4, 256, 0, stream>>>(p);
    k_fc <<<16, 1024, 0, stream>>>(p);
}

// Round 14
// 317.203 us; speedup vs baseline: 1.2156x; 1.0175x over previous
//
#include <hip/hip_runtime.h>
#include <hip/hip_bf16.h>
#include <math.h>

namespace {

typedef unsigned long long u64;
typedef __attribute__((ext_vector_type(8))) short bf16x8;
typedef __attribute__((ext_vector_type(4))) float f32x4;

constexpr int KK = 5;
constexpr int K3 = 125;
constexpr int N0 = 16384, E0 = 262144;
constexpr int N1 = 4096,  E1 = 65536;
constexpr int N2 = 1024,  E2 = 16384;
constexpr int N3 = 256,   E3 = 4096;
constexpr int E_TOT = E0 + E1 + E2 + E3;     // 348160
constexpr unsigned ENC_NEG_INF = 0x007FFFFFu;
constexpr int KO2 = K3 * 64, KO3 = K3 * 64, KO4 = K3 * 128;   // y row length (fp8 bytes)

// ---------------- workspace layout (float-slot offsets) ----------------
constexpr size_t A_PENC1 = 0;
constexpr size_t A_PENC2 = A_PENC1 + (size_t)N1 * 32;
constexpr size_t A_PENC3 = A_PENC2 + (size_t)N2 * 64;
constexpr size_t A_PENC4 = A_PENC3 + (size_t)N3 * 64;
constexpr size_t A_PENC_END = A_PENC4 + (size_t)128 * 128;
constexpr size_t PENC_TOTAL = A_PENC_END;                  // 229376

constexpr size_t A_WT2 = A_PENC_END;
constexpr size_t A_WT3 = A_WT2 + (size_t)K3 * 64 * 32 / 2;
constexpr size_t A_WT4 = A_WT3 + (size_t)K3 * 64 * 64 / 2;

constexpr size_t A_OFF0 = A_WT4 + (size_t)K3 * 128 * 64 / 2;
constexpr size_t A_OFF1 = A_OFF0 + (N0 + 4);
constexpr size_t A_OFF2 = A_OFF1 + (N1 + 4);
constexpr size_t A_OFF3 = A_OFF2 + (N2 + 4);
constexpr size_t A_CUR0 = A_OFF3 + (N3 + 4);
constexpr size_t A_CUR1 = A_CUR0 + N0;
constexpr size_t A_CUR2 = A_CUR1 + N1;
constexpr size_t A_CUR3 = A_CUR2 + N2;
constexpr size_t A_CUR_END = A_CUR3 + N3;
constexpr size_t CUR_TOTAL = A_CUR_END - A_CUR0;           // 21760

constexpr size_t A_REC0 = (A_CUR_END + 3) & ~(size_t)3;    // 8 floats (32B) per edge
constexpr size_t A_REC1 = A_REC0 + (size_t)E0 * 8;
constexpr size_t A_REC2 = A_REC1 + (size_t)E1 * 8;
constexpr size_t A_REC3 = A_REC2 + (size_t)E2 * 8;
constexpr size_t A_Y    = (A_REC3 + (size_t)E3 * 8 + 3) & ~(size_t)3;   // fp8 bytes from here

// grid partition constants
constexpr int NB_HIST  = (E_TOT + 255) / 256;  // 1360
constexpr int NB_SCAT0 = E0 / 256;             // 1024
constexpr int NB_SCAT1 = E1 / 256;             // 256
constexpr int NB_SCAT2 = E2 / 256;             // 64
constexpr int NB_SCAT3 = E3 / 256;             // 16
constexpr int NB_L1    = N0 / 8;               // 2048
constexpr int NB_G2    = (KO2 / 64) * ((N1 / 16) / 16);    // 125*16 = 2000
constexpr int NB_G3    = (KO3 / 64) * ((N2 / 16) / 16);    // 125*4  = 500
constexpr int NB_G4    = (KO4 / 64) * ((N3 / 16) / 16);    // 250*1  = 250
constexpr int NB_GA2   = N1 / 4;               // 1024
constexpr int NB_GA3   = N2 / 4;               // 256
constexpr int NB_GA4   = N3 / 4;               // 64

constexpr int STG_B_STRIDE = 80;               // fp8 row stride in LDS (16B-aligned)
constexpr int STG_B_WAVE = 16 * STG_B_STRIDE;  // 1280 B per wave

struct __align__(16) ERec {      // one CSR-ordered edge record (32 B)
    unsigned short bas[8];       // bf16 basis
    u64 kid;
    unsigned src;
    unsigned pad;
};

struct P {
    const float *x0, *W1, *root1, *b1, *root2, *b2, *root3, *b3, *root4, *b4;
    const float *ps0, *ps1, *ps2, *ps3;
    const float *W2, *W3, *W4, *fc1w, *fc1b, *fc2w, *fc2b;
    const int *src0, *dst0, *src1, *dst1, *src2, *dst2, *src3, *dst3;
    const int *cl0, *cl1, *cl2, *cl3;
    float* ws;
    float* out;
};

// ---------------- helpers ----------------
__device__ __forceinline__ float eluf(float x) { return x > 0.f ? x : expm1f(x); }

__device__ __forceinline__ unsigned enc_f(float x) {
    unsigned u = __float_as_uint(x);
    return (u & 0x80000000u) ? ~u : (u | 0x80000000u);
}
__device__ __forceinline__ float dec_fin(unsigned u) {
    u = (u & 0x80000000u) ? (u & 0x7fffffffu) : ~u;
    float v = __uint_as_float(u);
    return isfinite(v) ? v : 0.f;
}
__device__ __forceinline__ float bf2f(unsigned short u) {
    return __uint_as_float((unsigned)u << 16);
}
__device__ __forceinline__ unsigned short f2bf(float v) {
    __hip_bfloat16 h = __float2bfloat16(v);
    return *reinterpret_cast<unsigned short*>(&h);
}
__device__ __forceinline__ float fp8f(unsigned b) {
    return __builtin_amdgcn_cvt_f32_fp8((int)b, 0);
}

__device__ __forceinline__ void decode_edge(const float* __restrict__ pseudo, int e,
                                            float bas[8], int kid[8]) {
    float v0 = pseudo[e * 3 + 0] * (KK - 1);
    float v1 = pseudo[e * 3 + 1] * (KK - 1);
    float v2 = pseudo[e * 3 + 2] * (KK - 1);
    float f0 = fminf(fmaxf(floorf(v0), 0.f), (float)(KK - 2));
    float f1 = fminf(fmaxf(floorf(v1), 0.f), (float)(KK - 2));
    float f2 = fminf(fmaxf(floorf(v2), 0.f), (float)(KK - 2));
    int lo0 = (int)f0, lo1 = (int)f1, lo2 = (int)f2;
    float fr0 = v0 - f0, fr1 = v1 - f1, fr2 = v2 - f2;
#pragma unroll
    for (int c = 0; c < 8; ++c) {
        int b0 = c & 1, b1 = (c >> 1) & 1, b2 = (c >> 2) & 1;
        kid[c] = (lo0 + b0) + (lo1 + b1) * KK + (lo2 + b2) * KK * KK;
        bas[c] = (b0 ? fr0 : 1.f - fr0) * (b1 ? fr1 : 1.f - fr1) * (b2 ? fr2 : 1.f - fr2);
    }
}

// ---------------- unit: W[k][i][o] f32 -> wt[(k*OUT+o)][i] bf16 (32-row halves) ----
__device__ void wt_unit(const float* __restrict__ W, unsigned short* __restrict__ wt,
                        int IN, int OUT, int k, float* smem) {
    const float* Wk = W + (size_t)k * IN * OUT;
    unsigned short* wk = wt + (size_t)k * IN * OUT;
    int halves = IN / 32;
    for (int h = 0; h < halves; ++h) {
        __syncthreads();
        for (int idx = threadIdx.x; idx < 32 * OUT; idx += 256) {
            int i = idx / OUT, o = idx % OUT;
            smem[i * (OUT + 1) + o] = Wk[(size_t)(h * 32 + i) * OUT + o];
        }
        __syncthreads();
        for (int idx = threadIdx.x; idx < OUT * 32; idx += 256) {
            int o = idx / 32, i = idx % 32;
            wk[(size_t)o * IN + h * 32 + i] = f2bf(smem[i * (OUT + 1) + o]);
        }
    }
}

// ---------------- unit: decode + scatter one 256-edge slab into CSR records -------
__device__ void scat_unit(int u, const float* __restrict__ ps,
                          const int* __restrict__ dst, const int* __restrict__ srcA,
                          int* __restrict__ cur, ERec* __restrict__ rec, int E) {
    int e = u * 256 + threadIdx.x;
    if (e >= E) return;
    float b[8]; int k[8];
    decode_edge(ps, e, b, k);
    u64 pk = 0;
#pragma unroll
    for (int c = 0; c < 8; ++c) pk |= (u64)(unsigned)k[c] << (8 * c);
    int q = atomicAdd(&cur[dst[e]], 1);
    ERec r;
#pragma unroll
    for (int c = 0; c < 8; ++c) r.bas[c] = f2bf(b[c]);
    r.kid = pk;
    r.src = (unsigned)srcA[e];
    r.pad = 0;
    rec[q] = r;
}

// ---------------- unit: one 16n x 64ko MFMA tile, LDS-staged fp8 coalesced store --
template <int IN>
__device__ __forceinline__ void gemm_tile(int n0, int ko0,
                                          const unsigned* __restrict__ penc,
                                          const unsigned short* __restrict__ wt,
                                          unsigned char* __restrict__ y, int KO,
                                          unsigned char* __restrict__ stg) {
    int lane = threadIdx.x & 63;
    int l15 = lane & 15;
    int kk = (lane >> 4) << 3;
    int rbase = (lane >> 4) << 2;
    f32x4 acc[4];
#pragma unroll
    for (int t = 0; t < 4; ++t) acc[t] = (f32x4){0.f, 0.f, 0.f, 0.f};
#pragma unroll
    for (int s = 0; s < IN / 32; ++s) {
        const unsigned* pp = penc + (size_t)(n0 + l15) * IN + s * 32 + kk;
        uint4 u0 = *(const uint4*)pp;
        uint4 u1 = *(const uint4*)(pp + 4);
        unsigned uu[8] = {u0.x, u0.y, u0.z, u0.w, u1.x, u1.y, u1.z, u1.w};
        bf16x8 bfrag;
#pragma unroll
        for (int t = 0; t < 8; ++t) bfrag[t] = (short)f2bf(dec_fin(uu[t]));
#pragma unroll
        for (int t = 0; t < 4; ++t) {
            bf16x8 afrag = *(const bf16x8*)(wt + (size_t)(ko0 + t * 16 + l15) * IN + s * 32 + kk);
            acc[t] = __builtin_amdgcn_mfma_f32_16x16x32_bf16(afrag, bfrag, acc[t], 0, 0, 0);
        }
    }
    // stage tile into per-wave LDS as fp8: stg[n(l15)][koByte]
#pragma unroll
    for (int t = 0; t < 4; ++t) {
        int w = __builtin_amdgcn_cvt_pk_fp8_f32(acc[t][0], acc[t][1], 0, false);
        w = __builtin_amdgcn_cvt_pk_fp8_f32(acc[t][2], acc[t][3], w, true);
        *(unsigned*)(stg + l15 * STG_B_STRIDE + t * 16 + rbase) = (unsigned)w;
    }
    // coalesced write: 64 lanes x 16B = 16 rows x 64B (full tile)
    int row = lane >> 2;
    int off16 = (lane & 3) << 4;
    uint4 v = *(const uint4*)(stg + row * STG_B_STRIDE + off16);
    *(uint4*)(y + (size_t)(n0 + row) * KO + ko0 + off16) = v;
}

// block = one ko-group x 16 n-tiles (wt slice stays L1-hot)
template <int IN>
__device__ void gemm_blk(int bid, const unsigned* __restrict__ penc,
                         const unsigned short* __restrict__ wt,
                         unsigned char* __restrict__ y, int N, int KO,
                         unsigned char* __restrict__ stg_base) {
    int nGrp = (N >> 4) >> 4;
    int kog = bid / nGrp;
    int nchunk = bid % nGrp;
    int wsub = threadIdx.x >> 6;
    int ko0 = kog << 6;
    unsigned char* stg = stg_base + wsub * STG_B_WAVE;
#pragma unroll
    for (int it = 0; it < 4; ++it) {
        int ntile = (nchunk << 4) + (it << 2) + wsub;
        gemm_tile<IN>(ntile << 4, ko0, penc, wt, y, KO, stg);
    }
}

// ---------------- unit: 4 nodes of gather+agg+finish+pool (CSR stream, fp8 y) ----
template <int IN, int OUT>
__device__ void gather_unit(int u, const unsigned char* __restrict__ y,
                            const ERec* __restrict__ rec, const int* __restrict__ off,
                            const unsigned* __restrict__ penc_prev,
                            const float* __restrict__ root,
                            const float* __restrict__ bias,
                            const int* __restrict__ cl,
                            unsigned* __restrict__ penc) {
    constexpr int KO = K3 * OUT;
    constexpr int WPT = OUT / 64;
    int lane = threadIdx.x & 63;
    int wv = threadIdx.x >> 6;
    int n = u * 4 + wv;
    int s0 = off[n], s1 = off[n + 1];
    float acc0 = 0.f, acc1 = 0.f;
    int j = s0;
    for (; j + 2 <= s1; j += 2) {
        ERec ra = rec[j], rb = rec[j + 1];
        const unsigned char* ypa = y + (size_t)ra.src * KO + lane;
        const unsigned char* ypb = y + (size_t)rb.src * KO + lane;
        u64 ka = ra.kid, kb = rb.kid;
        float va[8], vb[8], va2[8], vb2[8];
#pragma unroll
        for (int c = 0; c < 8; ++c) {
            int kca = (int)((ka >> (8 * c)) & 255u);
            int kcb = (int)((kb >> (8 * c)) & 255u);
            va[c] = fp8f(ypa[(size_t)kca * OUT]);
            vb[c] = fp8f(ypb[(size_t)kcb * OUT]);
            if (WPT == 2) {
                va2[c] = fp8f(ypa[(size_t)kca * OUT + 64]);
                vb2[c] = fp8f(ypb[(size_t)kcb * OUT + 64]);
            }
        }
#pragma unroll
        for (int c = 0; c < 8; ++c) {
            float bac = bf2f(ra.bas[c]), bbc = bf2f(rb.bas[c]);
            acc0 = fmaf(bac, va[c], acc0);
            acc0 = fmaf(bbc, vb[c], acc0);
            if (WPT == 2) {
                acc1 = fmaf(bac, va2[c], acc1);
                acc1 = fmaf(bbc, vb2[c], acc1);
            }
        }
    }
    if (j < s1) {
        ERec r = rec[j];
        const unsigned char* yp = y + (size_t)r.src * KO + lane;
        u64 k8 = r.kid;
#pragma unroll
        for (int c = 0; c < 8; ++c) {
            int kc = (int)((k8 >> (8 * c)) & 255u);
            float bc = bf2f(r.bas[c]);
            acc0 = fmaf(bc, fp8f(yp[(size_t)kc * OUT]), acc0);
            if (WPT == 2) acc1 = fmaf(bc, fp8f(yp[(size_t)kc * OUT + 64]), acc1);
        }
    }
    float dg = fmaxf((float)(s1 - s0), 1.f);
    float accs[2] = {acc0, acc1};
#pragma unroll
    for (int w = 0; w < WPT; ++w) {
        int o = lane + 64 * w;
        float r = 0.f;
        for (int i = 0; i < IN; ++i)
            r = fmaf(dec_fin(penc_prev[(size_t)n * IN + i]), root[(size_t)i * OUT + o], r);
        float val = accs[w] / dg + r + bias[o];
        val = eluf(val);
        atomicMax(&penc[(size_t)cl[n] * OUT + o], enc_f(val));
    }
}

// ================= kernels =================

// K1: init penc + dst histogram (+ W2 transpose in tail blocks)
__global__ __launch_bounds__(256) void k_p1(P p) {
    __shared__ float smem[32 * 129];
    float* ws = p.ws;
    int bid = blockIdx.x;
    if (bid < NB_HIST) {
        int g = bid * 256 + threadIdx.x;
        if (g < (int)PENC_TOTAL) ((unsigned*)(ws + A_PENC1))[g] = ENC_NEG_INF;
        if (g >= E_TOT) return;
        const int* dst; int* cur; int e;
        if (g < E0)                { dst = p.dst0; cur = (int*)(ws + A_CUR0); e = g; }
        else if (g < E0 + E1)      { dst = p.dst1; cur = (int*)(ws + A_CUR1); e = g - E0; }
        else if (g < E0 + E1 + E2) { dst = p.dst2; cur = (int*)(ws + A_CUR2); e = g - E0 - E1; }
        else                       { dst = p.dst3; cur = (int*)(ws + A_CUR3); e = g - E0 - E1 - E2; }
        atomicAdd(&cur[dst[e]], 1);
    } else {
        wt_unit(p.W2, (unsigned short*)(ws + A_WT2), 32, 64, bid - NB_HIST, smem);
    }
}

// K2: exclusive scan per layer
__global__ __launch_bounds__(1024) void k_scan(P p) {
    __shared__ int ls[1024];
    float* ws = p.ws;
    int* cur; int* off; int N;
    switch (blockIdx.x) {
        case 0:  cur = (int*)(ws + A_CUR0); off = (int*)(ws + A_OFF0); N = N0; break;
        case 1:  cur = (int*)(ws + A_CUR1); off = (int*)(ws + A_OFF1); N = N1; break;
        case 2:  cur = (int*)(ws + A_CUR2); off = (int*)(ws + A_OFF2); N = N2; break;
        default: cur = (int*)(ws + A_CUR3); off = (int*)(ws + A_OFF3); N = N3; break;
    }
    int t = threadIdx.x;
    int chunk = (N + 1023) >> 10;
    int b0 = t * chunk;
    int b1 = min(b0 + chunk, N);
    int s = 0;
    for (int i = b0; i < b1; ++i) s += cur[i];
    ls[t] = s;
    __syncthreads();
    for (int d = 1; d < 1024; d <<= 1) {
        int v = (t >= d) ? ls[t - d] : 0;
        __syncthreads();
        ls[t] += v;
        __syncthreads();
    }
    int run = (t == 0) ? 0 : ls[t - 1];
    for (int i = b0; i < b1; ++i) {
        int c = cur[i];
        off[i] = run;
        cur[i] = run;
        run += c;
    }
    if (t == 1023) off[N] = run;
}

// K3: scatter-decode layer-0 edges into CSR records
__global__ __launch_bounds__(256) void k_p2(P p) {
    scat_unit(blockIdx.x, p.ps0, p.dst0, p.src0,
              (int*)(p.ws + A_CUR0), (ERec*)(p.ws + A_REC0), E0);
}

// K4: layer-1 aggregation (+ layer-1 edge scatter in tail blocks)
__global__ __launch_bounds__(256) void k_l1(P p) {
    __shared__ float wlds[K3 * 32];
    float* ws = p.ws;
    int bid = blockIdx.x;
    if (bid >= NB_L1) {
        scat_unit(bid - NB_L1, p.ps1, p.dst1, p.src1,
                  (int*)(ws + A_CUR1), (ERec*)(ws + A_REC1), E1);
        return;
    }
    for (int i = threadIdx.x; i < K3 * 32; i += 256) wlds[i] = p.W1[i];
    __syncthreads();
    const ERec* rec = (const ERec*)(ws + A_REC0);
    const int* off = (const int*)(ws + A_OFF0);
    unsigned* penc = (unsigned*)(ws + A_PENC1);
    int o = threadIdx.x & 31;
    int nsub = threadIdx.x >> 5;
    int n = bid * 8 + nsub;
    int s0 = off[n], s1 = off[n + 1];
    float acc = 0.f;
    int j = s0;
    for (; j + 2 <= s1; j += 2) {
        ERec ra = rec[j], rb = rec[j + 1];
        u64 ka = ra.kid, kb = rb.kid;
        float xa = p.x0[ra.src], xb = p.x0[rb.src];
        float ma, mb;
        ma  = bf2f(ra.bas[0]) * wlds[((int)( ka        & 255u)) * 32 + o];
        ma += bf2f(ra.bas[1]) * wlds[((int)((ka >>  8) & 255u)) * 32 + o];
        ma += bf2f(ra.bas[2]) * wlds[((int)((ka >> 16) & 255u)) * 32 + o];
        ma += bf2f(ra.bas[3]) * wlds[((int)((ka >> 24) & 255u)) * 32 + o];
        ma += bf2f(ra.bas[4]) * wlds[((int)((ka >> 32) & 255u)) * 32 + o];
        ma += bf2f(ra.bas[5]) * wlds[((int)((ka >> 40) & 255u)) * 32 + o];
        ma += bf2f(ra.bas[6]) * wlds[((int)((ka >> 48) & 255u)) * 32 + o];
        ma += bf2f(ra.bas[7]) * wlds[((int)((ka >> 56) & 255u)) * 32 + o];
        mb  = bf2f(rb.bas[0]) * wlds[((int)( kb        & 255u)) * 32 + o];
        mb += bf2f(rb.bas[1]) * wlds[((int)((kb >>  8) & 255u)) * 32 + o];
        mb += bf2f(rb.bas[2]) * wlds[((int)((kb >> 16) & 255u)) * 32 + o];
        mb += bf2f(rb.bas[3]) * wlds[((int)((kb >> 24) & 255u)) * 32 + o];
        mb += bf2f(rb.bas[4]) * wlds[((int)((kb >> 32) & 255u)) * 32 + o];
        mb += bf2f(rb.bas[5]) * wlds[((int)((kb >> 40) & 255u)) * 32 + o];
        mb += bf2f(rb.bas[6]) * wlds[((int)((kb >> 48) & 255u)) * 32 + o];
        mb += bf2f(rb.bas[7]) * wlds[((int)((kb >> 56) & 255u)) * 32 + o];
        acc = fmaf(xa, ma, fmaf(xb, mb, acc));
    }
    if (j < s1) {
        ERec r = rec[j];
        u64 k8 = r.kid;
        float xv = p.x0[r.src];
        float m;
        m  = bf2f(r.bas[0]) * wlds[((int)( k8        & 255u)) * 32 + o];
        m += bf2f(r.bas[1]) * wlds[((int)((k8 >>  8) & 255u)) * 32 + o];
        m += bf2f(r.bas[2]) * wlds[((int)((k8 >> 16) & 255u)) * 32 + o];
        m += bf2f(r.bas[3]) * wlds[((int)((k8 >> 24) & 255u)) * 32 + o];
        m += bf2f(r.bas[4]) * wlds[((int)((k8 >> 32) & 255u)) * 32 + o];
        m += bf2f(r.bas[5]) * wlds[((int)((k8 >> 40) & 255u)) * 32 + o];
        m += bf2f(r.bas[6]) * wlds[((int)((k8 >> 48) & 255u)) * 32 + o];
        m += bf2f(r.bas[7]) * wlds[((int)((k8 >> 56) & 255u)) * 32 + o];
        acc = fmaf(xv, m, acc);
    }
    float dg = fmaxf((float)(s1 - s0), 1.f);
    float val = acc / dg + p.x0[n] * p.root1[o] + p.b1[o];
    val = eluf(val);
    atomicMax(&penc[(size_t)p.cl0[n] * 32 + o], enc_f(val));
}

// K5: gemm layer-2 (+ L2 scatter + W3/W4 transpose in tail blocks)
__global__ __launch_bounds__(256) void k_g2(P p) {
    __shared__ float smem[32 * 129];   // 16.5 KB; gemm path uses first 5 KB as staging
    float* ws = p.ws;
    int bid = blockIdx.x;
    if (bid < NB_G2) {
        gemm_blk<32>(bid, (unsigned*)(ws + A_PENC1), (unsigned short*)(ws + A_WT2),
                     (unsigned char*)(ws + A_Y), N1, KO2, (unsigned char*)smem);
    } else if (bid < NB_G2 + NB_SCAT2) {
        scat_unit(bid - NB_G2, p.ps2, p.dst2, p.src2,
                  (int*)(ws + A_CUR2), (ERec*)(ws + A_REC2), E2);
    } else if (bid < NB_G2 + NB_SCAT2 + K3) {
        wt_unit(p.W3, (unsigned short*)(ws + A_WT3), 64, 64, bid - NB_G2 - NB_SCAT2, smem);
    } else {
        wt_unit(p.W4, (unsigned short*)(ws + A_WT4), 64, 128, bid - NB_G2 - NB_SCAT2 - K3, smem);
    }
}

// K6: gather layer-2 (+ L3 scatter in tail blocks)
__global__ __launch_bounds__(256) void k_ga2(P p) {
    float* ws = p.ws;
    int bid = blockIdx.x;
    if (bid < NB_GA2) {
        gather_unit<32, 64>(bid, (unsigned char*)(ws + A_Y), (const ERec*)(ws + A_REC1),
                            (const int*)(ws + A_OFF1), (unsigned*)(ws + A_PENC1),
                            p.root2, p.b2, p.cl1, (unsigned*)(ws + A_PENC2));
    } else {
        scat_unit(bid - NB_GA2, p.ps3, p.dst3, p.src3,
                  (int*)(ws + A_CUR3), (ERec*)(ws + A_REC3), E3);
    }
}

// K7-K10: layer 3/4 gemm+gather
__global__ __launch_bounds__(256) void k_g3(P p) {
    __shared__ unsigned char stg[4 * STG_B_WAVE];
    gemm_blk<64>(blockIdx.x, (unsigned*)(p.ws + A_PENC2), (unsigned short*)(p.ws + A_WT3),
                 (unsigned char*)(p.ws + A_Y), N2, KO3, stg);
}
__global__ __launch_bounds__(256) void k_ga3(P p) {
    gather_unit<64, 64>(blockIdx.x, (unsigned char*)(p.ws + A_Y), (const ERec*)(p.ws + A_REC2),
                        (const int*)(p.ws + A_OFF2), (unsigned*)(p.ws + A_PENC2),
                        p.root3, p.b3, p.cl2, (unsigned*)(p.ws + A_PENC3));
}
__global__ __launch_bounds__(256) void k_g4(P p) {
    __shared__ unsigned char stg[4 * STG_B_WAVE];
    gemm_blk<64>(blockIdx.x, (unsigned*)(p.ws + A_PENC3), (unsigned short*)(p.ws + A_WT4),
                 (unsigned char*)(p.ws + A_Y), N3, KO4, stg);
}
__global__ __launch_bounds__(256) void k_ga4(P p) {
    gather_unit<64, 128>(blockIdx.x, (unsigned char*)(p.ws + A_Y), (const ERec*)(p.ws + A_REC3),
                         (const int*)(p.ws + A_OFF3), (unsigned*)(p.ws + A_PENC3),
                         p.root4, p.b4, p.cl3, (unsigned*)(p.ws + A_PENC4));
}

// K11: fused FC head: fc1 + ELU + fc2 + log_softmax, one block per batch row
__global__ __launch_bounds__(1024) void k_fc(P p) {
    __shared__ float xs[1024];
    __shared__ float part[4][257];
    __shared__ float h[256];
    __shared__ float l[10];
    __shared__ float red[2];
    int bq = blockIdx.x;
    int t = threadIdx.x;
    const unsigned* penc4 = (const unsigned*)(p.ws + A_PENC4);
    xs[t] = dec_fin(penc4[(size_t)bq * 1024 + t]);
    __syncthreads();
    int o = t & 255, sl = t >> 8;
    const float* wp = p.fc1w + (size_t)(sl * 256) * 256 + o;
    const float* xp = xs + sl * 256;
    float acc = 0.f;
#pragma unroll 8
    for (int k = 0; k < 256; ++k)
        acc = fmaf(xp[k], wp[(size_t)k * 256], acc);
    part[sl][o] = acc;
    __syncthreads();
    if (t < 256) {
        float v = part[0][t] + part[1][t] + part[2][t] + part[3][t] + p.fc1b[t];
        h[t] = eluf(v);
    }
    __syncthreads();
    if (t < 10) {
        float a2 = p.fc2b[t];
        for (int q = 0; q < 256; ++q)
            a2 = fmaf(h[q], p.fc2w[(size_t)q * 10 + t], a2);
        l[t] = a2;
    }
    __syncthreads();
    if (t == 0) {
        float m = l[0];
        for (int i = 1; i < 10; ++i) m = fmaxf(m, l[i]);
        float s = 0.f;
        for (int i = 0; i < 10; ++i) s += expf(l[i] - m);
        red[0] = m;
        red[1] = logf(s);
    }
    __syncthreads();
    if (t < 10) p.out[(size_t)bq * 10 + t] = l[t] - red[0] - red[1];
}

} // namespace

extern "C" void kernel_launch(void* const* d_in, const int* in_sizes, int n_in,
                              void* d_out, int out_size, void* d_ws, size_t ws_size,
                              hipStream_t stream) {
    P p;
    p.x0    = (const float*)d_in[0];
    p.ps0   = (const float*)d_in[1];
    p.ps1   = (const float*)d_in[2];
    p.ps2   = (const float*)d_in[3];
    p.ps3   = (const float*)d_in[4];
    p.W1    = (const float*)d_in[5];
    p.root1 = (const float*)d_in[6];
    p.b1    = (const float*)d_in[7];
    p.W2    = (const float*)d_in[8];
    p.root2 = (const float*)d_in[9];
    p.b2    = (const float*)d_in[10];
    p.W3    = (const float*)d_in[11];
    p.root3 = (const float*)d_in[12];
    p.b3    = (const float*)d_in[13];
    p.W4    = (const float*)d_in[14];
    p.root4 = (const float*)d_in[15];
    p.b4    = (const float*)d_in[16];
    p.fc1w  = (const float*)d_in[17];
    p.fc1b  = (const float*)d_in[18];
    p.fc2w  = (const float*)d_in[19];
    p.fc2b  = (const float*)d_in[20];
    p.src0 = (const int*)d_in[21];
    p.dst0 = (const int*)d_in[22];
    p.src1 = (const int*)d_in[23];
    p.dst1 = (const int*)d_in[24];
    p.src2 = (const int*)d_in[25];
    p.dst2 = (const int*)d_in[26];
    p.src3 = (const int*)d_in[27];
    p.dst3 = (const int*)d_in[28];
    p.cl0  = (const int*)d_in[29];
    p.cl1  = (const int*)d_in[30];
    p.cl2  = (const int*)d_in[31];
    p.cl3  = (const int*)d_in[32];
    p.ws = (float*)d_ws;
    p.out = (float*)d_out;

    hipMemsetAsync(p.ws + A_CUR0, 0, CUR_TOTAL * sizeof(int), stream);

    k_p1 <<<NB_HIST + K3, 256, 0, stream>>>(p);
    k_scan<<<4, 1024, 0, stream>>>(p);
    k_p2 <<<NB_SCAT0, 256, 0, stream>>>(p);
    k_l1 <<<NB_L1 + NB_SCAT1, 256, 0, stream>>>(p);
    k_g2 <<<NB_G2 + NB_SCAT2 + 2 * K3, 256, 0, stream>>>(p);
    k_ga2<<<NB_GA2 + NB_SCAT3, 256, 0, stream>>>(p);
    k_g3 <<<NB_G3, 256, 0, stream>>>(p);
    k_ga3<<<NB_GA3, 256, 0, stream>>>(p);
    k_g4 <<<NB_G4, 256, 0, stream>>>(p);
    k_ga4<<<NB_GA4, 256, 0, stream>>>(p);
    k_fc <<<16, 1024, 0, stream>>>(p);
}